// Round 29
// baseline (109.625 us; speedup 1.0000x reference)
//
#include <hip/hip_runtime.h>
#include <stdint.h>

#pragma clang fp contract(off)

// ---------------------------------------------------------------------------
// Binary ConvBlock, bit-exact to the fp32 numpy reference (validated r5-r28):
//   - stage 1: conv1x1(x, sgn w11): SEQUENTIAL fp32 chain over ci=0..255
//     ascending via fma(+-1.0f, x, acc) == fl(acc +- x). fp32 BN threshold.
//   - stages 2-4: exact-integer popcount convs, fp32 BN threshold:
//       inv = g/sqrt(v+1e-4f); beta = b - m*inv; val = y*inv + beta.
// r29 = r28 + k1 double-buffer WITH T19 enforcement: r28's [8 VMEM][256
//   VALU] grouping worked (47->44us, first k1 movement in 20 rounds) but
//   loads still sat directly before their consumers (one ~500cy wait per
//   iteration exposed). Now loads for batch k+1 issue before compute of
//   batch k (r12's dbuf, which the scheduler defeated unaided), pinned by
//   sched_group_barrier pairs; last iteration peeled (branch-free body).
//   k1: float4 392x256; conv3c: lane = pixel, s_load weights;
//   conv3#1 fuses k3; k0: single fused prep. H/S planar [quarter][px].
// B=16, Cin=256, down=64, up=256, H=W=56.
// ---------------------------------------------------------------------------

#define HW_   3136          // 56*56
#define NPIX  50176         // 16*3136

// workspace layout (bytes)
#define OFF_W31B   0         // 2304 u64 ([co][tap])
#define OFF_W12B   18432     // 256 u64  ([co][k])
#define OFF_W32B   20480     // 2304 u64
#define OFF_IV11   38912     // 64 float2
#define OFF_IV31   39424     // 256 float2
#define OFF_IV12   41472     // 64 float2
#define OFF_IV32   41984     // 256 float2
#define OFF_SGNT   44032     // 16384 f32 (+-1.0f, [ci][j]) = 64 KiB
#define OFF_A1     109568    // 50176 u64 (byte g = ch 8g..8g+7)
#define OFF_A2     510976    // 50176 u64 (u16 quarter per wave)
#define OFF_H      912384    // 4 planes x 50176 u64 (bit = co within quarter)
#define OFF_S      2518016   // 4 planes x 50176 u64

__device__ inline float2 mk_ivbt(float g, float b, float m, float v) {
    float inv  = __fdiv_rn(g, __fsqrt_rn(__fadd_rn(v, 1e-4f)));
    float beta = __fsub_rn(b, __fmul_rn(m, inv));
    return make_float2(inv, beta);
}

// ------------- K0: fused prep (pack weights + BN + sign table) -------------
// blocks [0,1216): ballot weight packing (wave per u64 word)
// blocks [1216,1219): BN (inv,beta)    blocks [1219,1283): sgnT
__global__ __launch_bounds__(256) void k0_all(
    const float* __restrict__ w11, const float* __restrict__ w31,
    const float* __restrict__ w12, const float* __restrict__ w32,
    const float* __restrict__ g11, const float* __restrict__ b11,
    const float* __restrict__ m11, const float* __restrict__ v11,
    const float* __restrict__ g31, const float* __restrict__ b31,
    const float* __restrict__ m31, const float* __restrict__ v31,
    const float* __restrict__ g12, const float* __restrict__ b12,
    const float* __restrict__ m12, const float* __restrict__ v12,
    const float* __restrict__ g32, const float* __restrict__ b32,
    const float* __restrict__ m32, const float* __restrict__ v32,
    uint64_t* __restrict__ W31b, uint64_t* __restrict__ W12b,
    uint64_t* __restrict__ W32b,
    float2* __restrict__ iv11, float2* __restrict__ iv31,
    float2* __restrict__ iv12, float2* __restrict__ iv32,
    float* __restrict__ sgnT)
{
    int blk = blockIdx.x;
    if (blk < 1216) {                        // ---- weight bit packing ----
        int wid = blk * 4 + (threadIdx.x >> 6);
        int l = threadIdx.x & 63;
        if (wid < 2304) {                    // W31b[co*9+tap]: bit ci = lane
            int co = wid / 9, tap = wid % 9;
            uint64_t bits = __ballot(w31[(co * 64 + l) * 9 + tap] >= 0.f);
            if (l == 0) W31b[wid] = bits;
        } else if (wid < 4608) {             // W32b
            int i = wid - 2304;
            int co = i / 9, tap = i % 9;
            uint64_t bits = __ballot(w32[(co * 64 + l) * 9 + tap] >= 0.f);
            if (l == 0) W32b[i] = bits;
        } else if (wid < 4864) {             // W12b[co*4+k]: bit ci' = lane
            int i = wid - 4608;
            int co = i >> 2, k = i & 3;
            uint64_t bits = __ballot(w12[co * 256 + k * 64 + l] >= 0.f);
            if (l == 0) W12b[i] = bits;
        }
    } else if (blk < 1219) {                 // ---- BN (inv, beta) ----
        int i = (blk - 1216) * 256 + threadIdx.x;
        if (i < 64)        iv11[i]       = mk_ivbt(g11[i],       b11[i],       m11[i],       v11[i]);
        else if (i < 320)  iv31[i - 64]  = mk_ivbt(g31[i - 64],  b31[i - 64],  m31[i - 64],  v31[i - 64]);
        else if (i < 384)  iv12[i - 320] = mk_ivbt(g12[i - 320], b12[i - 320], m12[i - 320], v12[i - 320]);
        else if (i < 640)  iv32[i - 384] = mk_ivbt(g32[i - 384], b32[i - 384], m32[i - 384], v32[i - 384]);
    } else {                                 // ---- sign table [ci][j] ----
        int t = (blk - 1219) * 256 + threadIdx.x;   // t = j*256 + ci
        int j = t >> 8, ci = t & 255;
        sgnT[ci * 64 + j] = (w11[t] >= 0.f) ? 1.0f : -1.0f;
    }
}

// ------------- K1: fp32 SEQUENTIAL conv1x1 (x * sgn w11) + sign ------------
// grid 392 (= 196 px-chunks x 2 ch-halves), block 256 = 4 waves (ch-groups).
// lane l owns 4 consecutive pixels (float4). Wave wv owns channels
// [(half*4+wv)*8, +8). Double-buffered loads (batch k+1 issues before
// compute of batch k) pinned by sched_group_barrier [8 VMEM_READ][256 VALU]
// pairs; last iteration peeled so the loop body is branch-free.
__global__ __launch_bounds__(256, 1) void k1_conv1(
    const float* __restrict__ x, const float* __restrict__ sgnT,
    const float2* __restrict__ ivbt, unsigned char* __restrict__ A1)
{
    const int l = threadIdx.x & 63;
    const int wv = __builtin_amdgcn_readfirstlane(threadIdx.x >> 6);  // 0..3
    const int blk = blockIdx.x;               // 0..391
    const int half = blk & 1;
    const int g = half * 4 + wv;               // ch-group 0..7
    const int P = (blk >> 1) * 256 + l * 4;    // global pixel (3136 % 4 == 0)
    const int bl = P / HW_;
    const int pxl = P - bl * HW_;
    const float* xp = x + (size_t)bl * (256 * HW_) + pxl;
    const float* sg = sgnT + g * 8;            // [ci][64] + g*8

    float acc[8][4];
#pragma unroll
    for (int j = 0; j < 8; ++j)
#pragma unroll
        for (int p = 0; p < 4; ++p) acc[j][p] = 0.0f;

    float4 bufA[8], bufB[8];

#define PF(B, CI0)                                                          \
    _Pragma("unroll")                                                       \
    for (int k = 0; k < 8; ++k)                                             \
        B[k] = *(const float4*)(xp + (size_t)((CI0) + k) * HW_);

#define COMP(B, CI0)                                                        \
    _Pragma("unroll")                                                       \
    for (int k = 0; k < 8; ++k) {                                           \
        const float* s_ = sg + ((CI0) + k) * 64;                            \
        _Pragma("unroll")                                                   \
        for (int j = 0; j < 8; ++j) {                                       \
            acc[j][0] = __builtin_fmaf(s_[j], B[k].x, acc[j][0]);           \
            acc[j][1] = __builtin_fmaf(s_[j], B[k].y, acc[j][1]);           \
            acc[j][2] = __builtin_fmaf(s_[j], B[k].z, acc[j][2]);           \
            acc[j][3] = __builtin_fmaf(s_[j], B[k].w, acc[j][3]);           \
        }                                                                   \
    }

#define SGB_PAIR                                                            \
    __builtin_amdgcn_sched_group_barrier(0x020, 8, 0);                      \
    __builtin_amdgcn_sched_group_barrier(0x002, 256, 0);

    PF(bufA, 0)
    for (int cb = 0; cb < 240; cb += 16) {    // ci strictly ascending
        PF(bufB, cb + 8)
        COMP(bufA, cb)
        SGB_PAIR
        PF(bufA, cb + 16)
        COMP(bufB, cb + 8)
        SGB_PAIR
    }
    // tail: cb = 240
    PF(bufB, 248)
    COMP(bufA, 240)
    SGB_PAIR
    COMP(bufB, 248)
    __builtin_amdgcn_sched_group_barrier(0x002, 256, 0);

#undef PF
#undef COMP
#undef SGB_PAIR

    unsigned bp0 = 0, bp1 = 0, bp2 = 0, bp3 = 0;
#pragma unroll
    for (int j = 0; j < 8; ++j) {
        float2 ib = ivbt[g * 8 + j];
        bp0 |= (__fadd_rn(__fmul_rn(acc[j][0], ib.x), ib.y) >= 0.0f) ? (1u << j) : 0u;
        bp1 |= (__fadd_rn(__fmul_rn(acc[j][1], ib.x), ib.y) >= 0.0f) ? (1u << j) : 0u;
        bp2 |= (__fadd_rn(__fmul_rn(acc[j][2], ib.x), ib.y) >= 0.0f) ? (1u << j) : 0u;
        bp3 |= (__fadd_rn(__fmul_rn(acc[j][3], ib.x), ib.y) >= 0.0f) ? (1u << j) : 0u;
    }
    // byte g of per-pixel u64 word (bit j_global = g*8 + j), pixels P..P+3
    unsigned char* a = A1 + (size_t)P * 8 + g;
    a[0]  = (unsigned char)bp0;
    a[8]  = (unsigned char)bp1;
    a[16] = (unsigned char)bp2;
    a[24] = (unsigned char)bp3;
}

// ---- conv3x3, lane = pixel: 64ch bits -> 256ch bits (planar out) ----------
// grid 784, block 256 = 4 waves; wave = co-quarter, LANE = PIXEL.
// Taps + boundary masks in VGPRs (9 ds_reads/lane, once); weights wave-
// uniform via s_load (readfirstlane'd quarter). Per co:
//   y = 64*nv - 2*sum_t popc((a_t ^ w_t) & m_t)   (zero-padded tile).
// MERGE ORs Hin plane. DO_K3: A2 = sign(bn12(conv1x1(H, sgn w12))) via LDS
// exchange of the 4 quarters (exact-integer popcount, fp32 BN).
template <bool MERGE, bool DO_K3>
__global__ __launch_bounds__(256) void k_conv3c(
    const uint64_t* __restrict__ A, const uint64_t* __restrict__ Wb,
    const float2* __restrict__ ivbt, const uint64_t* __restrict__ Hin,
    uint64_t* __restrict__ Out,
    const uint64_t* __restrict__ W12b, const float2* __restrict__ iv12,
    unsigned short* __restrict__ A2)
{
    __shared__ uint64_t tile[4 * 58];
    __shared__ uint64_t sh4[4][64];
    const int l = threadIdx.x & 63;
    const int wv = threadIdx.x >> 6;
    const int wvu = __builtin_amdgcn_readfirstlane(wv);   // uniform quarter id
    const int chunk = blockIdx.x;            // 0..783
    const int b = chunk / 49;
    const int hw0 = (chunk % 49) * 64;
    const int r0 = hw0 / 56;
    const int o  = hw0 % 56;                 // 0..48 (chunk spans rows r0,r0+1)
    const int rfirst = r0 - 1;

    // stage zero-padded tile rows rfirst..rfirst+3, cols -1..56
    {
        int idx = threadIdx.x;
        if (idx < 4 * 58) {
            int rr = idx / 58, cc = idx % 58;
            int gh = rfirst + rr, gw = cc - 1;
            uint64_t v = 0;
            if ((unsigned)gh < 56u && (unsigned)gw < 56u)
                v = A[b * HW_ + gh * 56 + gw];
            tile[idx] = v;
        }
    }
    __syncthreads();

    // per-lane pixel coordinates
    const int inrow2 = (l >= 56 - o) ? 1 : 0;
    const int w = o + l - (inrow2 ? 56 : 0);
    const int row = r0 + inrow2;
    const int rbase = inrow2 * 58;

    // 9 taps + masks into VGPRs (once)
    uint64_t a[9], m[9];
    int nv = 0;
#pragma unroll
    for (int dr = 0; dr < 3; ++dr)
#pragma unroll
        for (int dc = 0; dc < 3; ++dc) {
            int t = dr * 3 + dc;
            a[t] = tile[rbase + dr * 58 + w + dc];   // zero-padded
            bool ok = ((unsigned)(row + dr - 1) < 56u) &&
                      ((unsigned)(w + dc - 1) < 56u);
            m[t] = ok ? ~0ull : 0ull;
            nv += ok;
        }
    const int base = 64 * nv;

    const uint64_t* wbase = Wb + wvu * 64 * 9;       // uniform
    const float2*   ivb   = ivbt + wvu * 64;         // uniform

    uint64_t bits = 0;
#pragma unroll 4
    for (int jo = 0; jo < 64; ++jo) {
        const uint64_t* wq = wbase + jo * 9;         // uniform -> s_load
        int s = 0;
#pragma unroll
        for (int t = 0; t < 9; ++t)
            s += (int)__popcll((a[t] ^ wq[t]) & m[t]);
        int y = base - 2 * s;
        float2 ib = ivb[jo];
        float val = __fadd_rn(__fmul_rn((float)y, ib.x), ib.y);
        bits |= (uint64_t)(val >= 0.0f) << jo;
    }

    size_t oidx = (size_t)wv * NPIX + (size_t)(b * HW_) + hw0 + l;
    if (MERGE) bits |= Hin[oidx];
    Out[oidx] = bits;

    if (DO_K3) {
        sh4[wv][l] = bits;
        __syncthreads();
        uint64_t h0 = sh4[0][l], h1 = sh4[1][l], h2 = sh4[2][l], h3 = sh4[3][l];
        unsigned bits16 = 0;
#pragma unroll
        for (int jj = 0; jj < 16; ++jj) {
            int cq = wvu * 16 + jj;                  // output channel 0..63
            const uint64_t* wq = W12b + cq * 4;      // uniform -> s_load
            int s = (int)(__popcll(h0 ^ wq[0]) + __popcll(h1 ^ wq[1]) +
                          __popcll(h2 ^ wq[2]) + __popcll(h3 ^ wq[3]));
            int y = 256 - 2 * s;
            float2 ibq = iv12[cq];
            float val = __fadd_rn(__fmul_rn((float)y, ibq.x), ibq.y);
            bits16 |= (val >= 0.0f) ? (1u << jj) : 0u;
        }
        // u16 quarter wv of A2[px] (bit cq = wv*16 + jj)
        A2[(size_t)(b * HW_ + hw0 + l) * 4 + wv] = (unsigned short)bits16;
    }
}

// ------------- K4b: OR-pool 2x2 (planar S) + write +-1.0f ------------------
__global__ __launch_bounds__(256) void k4b_pool(
    const uint64_t* __restrict__ S, float* __restrict__ out)
{
    int o = blockIdx.x * 256 + threadIdx.x;   // < 16*256*28*28 = 3211264
    int ow = o % 28;
    int t = o / 28;
    int oh = t % 28; t /= 28;
    int co = t & 255;
    int b  = t >> 8;
    int k = co >> 6, j = co & 63;
    const uint64_t* Sk = S + (size_t)k * NPIX + (size_t)(b * HW_) + (2 * oh) * 56 + 2 * ow;
    uint64_t s = Sk[0] | Sk[1] | Sk[56] | Sk[57];
    out[o] = ((s >> j) & 1) ? 1.0f : -1.0f;
}

// ---------------------------------------------------------------------------
extern "C" void kernel_launch(void* const* d_in, const int* in_sizes, int n_in,
                              void* d_out, int out_size, void* d_ws, size_t ws_size,
                              hipStream_t stream)
{
    const float* x   = (const float*)d_in[0];
    const float* w11 = (const float*)d_in[1];
    const float* w31 = (const float*)d_in[2];
    const float* w12 = (const float*)d_in[3];
    const float* w32 = (const float*)d_in[4];
    const float* g11 = (const float*)d_in[5];
    const float* b11 = (const float*)d_in[6];
    const float* m11 = (const float*)d_in[7];
    const float* v11 = (const float*)d_in[8];
    const float* g31 = (const float*)d_in[9];
    const float* b31 = (const float*)d_in[10];
    const float* m31 = (const float*)d_in[11];
    const float* v31 = (const float*)d_in[12];
    const float* g12 = (const float*)d_in[13];
    const float* b12 = (const float*)d_in[14];
    const float* m12 = (const float*)d_in[15];
    const float* v12 = (const float*)d_in[16];
    const float* g32 = (const float*)d_in[17];
    const float* b32 = (const float*)d_in[18];
    const float* m32 = (const float*)d_in[19];
    const float* v32 = (const float*)d_in[20];

    char* ws = (char*)d_ws;
    uint64_t* W31b = (uint64_t*)(ws + OFF_W31B);
    uint64_t* W12b = (uint64_t*)(ws + OFF_W12B);
    uint64_t* W32b = (uint64_t*)(ws + OFF_W32B);
    float2* iv11 = (float2*)(ws + OFF_IV11);
    float2* iv31 = (float2*)(ws + OFF_IV31);
    float2* iv12 = (float2*)(ws + OFF_IV12);
    float2* iv32 = (float2*)(ws + OFF_IV32);
    float*  sgnT = (float*)(ws + OFF_SGNT);
    uint64_t* A1 = (uint64_t*)(ws + OFF_A1);
    uint64_t* A2 = (uint64_t*)(ws + OFF_A2);
    uint64_t* Hb = (uint64_t*)(ws + OFF_H);
    uint64_t* Sb = (uint64_t*)(ws + OFF_S);

    k0_all<<<dim3(1283), dim3(256), 0, stream>>>(
        w11, w31, w12, w32,
        g11, b11, m11, v11, g31, b31, m31, v31,
        g12, b12, m12, v12, g32, b32, m32, v32,
        W31b, W12b, W32b, iv11, iv31, iv12, iv32, sgnT);

    k1_conv1<<<dim3(392), dim3(256), 0, stream>>>(x, sgnT, iv11, (unsigned char*)A1);

    // conv3 stage-2 with fused stage-3 conv1x1 (A2)
    k_conv3c<false, true><<<dim3(784), dim3(256), 0, stream>>>(
        A1, W31b, iv31, (const uint64_t*)nullptr, Hb,
        W12b, iv12, (unsigned short*)A2);

    // conv3 stage-4 with residual merge
    k_conv3c<true, false><<<dim3(784), dim3(256), 0, stream>>>(
        A2, W32b, iv32, Hb, Sb,
        (const uint64_t*)nullptr, (const float2*)nullptr, (unsigned short*)nullptr);

    k4b_pool<<<dim3(12544), dim3(256), 0, stream>>>(Sb, (float*)d_out);
}

// Round 30
// 109.241 us; speedup vs baseline: 1.0035x; 1.0035x over previous
//
#include <hip/hip_runtime.h>
#include <stdint.h>

#pragma clang fp contract(off)

// ---------------------------------------------------------------------------
// Binary ConvBlock, bit-exact to the fp32 numpy reference (validated r5-r29).
// FINAL = r28 (best measured: 109.44us; r29's dbuf+T19 was neutral).
//   - stage 1: conv1x1(x, sgn w11): SEQUENTIAL fp32 chain over ci=0..255
//     ascending via fma(+-1.0f, x, acc) == fl(acc +- x). fp32 BN threshold.
//   - stages 2-4: exact-integer popcount convs, fp32 BN threshold:
//       inv = g/sqrt(v+1e-4f); beta = b - m*inv; val = y*inv + beta.
// k1: float4 392x256 + sched_group_barrier [8 VMEM_READ][256 VALU] per
//   ci-iteration (T19; the one scheduling lever that moved k1: 47->44us).
// conv3c: lane = pixel, taps+masks in VGPRs once, s_load weights.
// conv3#1 fuses k3 (stage-3 conv1x1) via LDS exchange (saves ~8us).
// k0: single fused prep kernel. H/S planar [quarter][px].
// B=16, Cin=256, down=64, up=256, H=W=56.
// ---------------------------------------------------------------------------

#define HW_   3136          // 56*56
#define NPIX  50176         // 16*3136

// workspace layout (bytes)
#define OFF_W31B   0         // 2304 u64 ([co][tap])
#define OFF_W12B   18432     // 256 u64  ([co][k])
#define OFF_W32B   20480     // 2304 u64
#define OFF_IV11   38912     // 64 float2
#define OFF_IV31   39424     // 256 float2
#define OFF_IV12   41472     // 64 float2
#define OFF_IV32   41984     // 256 float2
#define OFF_SGNT   44032     // 16384 f32 (+-1.0f, [ci][j]) = 64 KiB
#define OFF_A1     109568    // 50176 u64 (byte g = ch 8g..8g+7)
#define OFF_A2     510976    // 50176 u64 (u16 quarter per wave)
#define OFF_H      912384    // 4 planes x 50176 u64 (bit = co within quarter)
#define OFF_S      2518016   // 4 planes x 50176 u64

__device__ inline float2 mk_ivbt(float g, float b, float m, float v) {
    float inv  = __fdiv_rn(g, __fsqrt_rn(__fadd_rn(v, 1e-4f)));
    float beta = __fsub_rn(b, __fmul_rn(m, inv));
    return make_float2(inv, beta);
}

// ------------- K0: fused prep (pack weights + BN + sign table) -------------
// blocks [0,1216): ballot weight packing (wave per u64 word)
// blocks [1216,1219): BN (inv,beta)    blocks [1219,1283): sgnT
__global__ __launch_bounds__(256) void k0_all(
    const float* __restrict__ w11, const float* __restrict__ w31,
    const float* __restrict__ w12, const float* __restrict__ w32,
    const float* __restrict__ g11, const float* __restrict__ b11,
    const float* __restrict__ m11, const float* __restrict__ v11,
    const float* __restrict__ g31, const float* __restrict__ b31,
    const float* __restrict__ m31, const float* __restrict__ v31,
    const float* __restrict__ g12, const float* __restrict__ b12,
    const float* __restrict__ m12, const float* __restrict__ v12,
    const float* __restrict__ g32, const float* __restrict__ b32,
    const float* __restrict__ m32, const float* __restrict__ v32,
    uint64_t* __restrict__ W31b, uint64_t* __restrict__ W12b,
    uint64_t* __restrict__ W32b,
    float2* __restrict__ iv11, float2* __restrict__ iv31,
    float2* __restrict__ iv12, float2* __restrict__ iv32,
    float* __restrict__ sgnT)
{
    int blk = blockIdx.x;
    if (blk < 1216) {                        // ---- weight bit packing ----
        int wid = blk * 4 + (threadIdx.x >> 6);
        int l = threadIdx.x & 63;
        if (wid < 2304) {                    // W31b[co*9+tap]: bit ci = lane
            int co = wid / 9, tap = wid % 9;
            uint64_t bits = __ballot(w31[(co * 64 + l) * 9 + tap] >= 0.f);
            if (l == 0) W31b[wid] = bits;
        } else if (wid < 4608) {             // W32b
            int i = wid - 2304;
            int co = i / 9, tap = i % 9;
            uint64_t bits = __ballot(w32[(co * 64 + l) * 9 + tap] >= 0.f);
            if (l == 0) W32b[i] = bits;
        } else if (wid < 4864) {             // W12b[co*4+k]: bit ci' = lane
            int i = wid - 4608;
            int co = i >> 2, k = i & 3;
            uint64_t bits = __ballot(w12[co * 256 + k * 64 + l] >= 0.f);
            if (l == 0) W12b[i] = bits;
        }
    } else if (blk < 1219) {                 // ---- BN (inv, beta) ----
        int i = (blk - 1216) * 256 + threadIdx.x;
        if (i < 64)        iv11[i]       = mk_ivbt(g11[i],       b11[i],       m11[i],       v11[i]);
        else if (i < 320)  iv31[i - 64]  = mk_ivbt(g31[i - 64],  b31[i - 64],  m31[i - 64],  v31[i - 64]);
        else if (i < 384)  iv12[i - 320] = mk_ivbt(g12[i - 320], b12[i - 320], m12[i - 320], v12[i - 320]);
        else if (i < 640)  iv32[i - 384] = mk_ivbt(g32[i - 384], b32[i - 384], m32[i - 384], v32[i - 384]);
    } else {                                 // ---- sign table [ci][j] ----
        int t = (blk - 1219) * 256 + threadIdx.x;   // t = j*256 + ci
        int j = t >> 8, ci = t & 255;
        sgnT[ci * 64 + j] = (w11[t] >= 0.f) ? 1.0f : -1.0f;
    }
}

// ------------- K1: fp32 SEQUENTIAL conv1x1 (x * sgn w11) + sign ------------
// grid 392 (= 196 px-chunks x 2 ch-halves), block 256 = 4 waves (ch-groups).
// lane l owns 4 consecutive pixels (float4 = 1KB/wave-request). Wave wv
// owns channels [ (half*4+wv)*8, +8 ). Barrier-free; signs via s_load.
// sched_group_barrier: force [8x VMEM_READ][256x VALU] per ci-iteration so
// all 8 loads pipeline (scheduler otherwise rolls them: VGPR=36 evidence).
__global__ __launch_bounds__(256, 1) void k1_conv1(
    const float* __restrict__ x, const float* __restrict__ sgnT,
    const float2* __restrict__ ivbt, unsigned char* __restrict__ A1)
{
    const int l = threadIdx.x & 63;
    const int wv = __builtin_amdgcn_readfirstlane(threadIdx.x >> 6);  // 0..3
    const int blk = blockIdx.x;               // 0..391
    const int half = blk & 1;
    const int g = half * 4 + wv;               // ch-group 0..7
    const int P = (blk >> 1) * 256 + l * 4;    // global pixel (3136 % 4 == 0)
    const int bl = P / HW_;
    const int pxl = P - bl * HW_;
    const float* xp = x + (size_t)bl * (256 * HW_) + pxl;
    const float* sg = sgnT + g * 8;            // [ci][64] + g*8

    float acc[8][4];
#pragma unroll
    for (int j = 0; j < 8; ++j)
#pragma unroll
        for (int p = 0; p < 4; ++p) acc[j][p] = 0.0f;

    for (int ci = 0; ci < 256; ci += 8) {      // ci ascending
        float4 xv[8];
#pragma unroll
        for (int k = 0; k < 8; ++k)
            xv[k] = *(const float4*)(xp + (size_t)(ci + k) * HW_);
#pragma unroll
        for (int k = 0; k < 8; ++k) {
            const float* s = sg + (ci + k) * 64;
#pragma unroll
            for (int j = 0; j < 8; ++j) {
                acc[j][0] = __builtin_fmaf(s[j], xv[k].x, acc[j][0]);
                acc[j][1] = __builtin_fmaf(s[j], xv[k].y, acc[j][1]);
                acc[j][2] = __builtin_fmaf(s[j], xv[k].z, acc[j][2]);
                acc[j][3] = __builtin_fmaf(s[j], xv[k].w, acc[j][3]);
            }
        }
        // T19: cluster the 8 VMEM reads ahead of the 256-fma VALU block
        // (masks per LLVM SchedGroupMask: VMEM_READ=0x20, VALU=0x2)
        __builtin_amdgcn_sched_group_barrier(0x020, 8, 0);
        __builtin_amdgcn_sched_group_barrier(0x002, 256, 0);
    }

    unsigned bp0 = 0, bp1 = 0, bp2 = 0, bp3 = 0;
#pragma unroll
    for (int j = 0; j < 8; ++j) {
        float2 ib = ivbt[g * 8 + j];
        bp0 |= (__fadd_rn(__fmul_rn(acc[j][0], ib.x), ib.y) >= 0.0f) ? (1u << j) : 0u;
        bp1 |= (__fadd_rn(__fmul_rn(acc[j][1], ib.x), ib.y) >= 0.0f) ? (1u << j) : 0u;
        bp2 |= (__fadd_rn(__fmul_rn(acc[j][2], ib.x), ib.y) >= 0.0f) ? (1u << j) : 0u;
        bp3 |= (__fadd_rn(__fmul_rn(acc[j][3], ib.x), ib.y) >= 0.0f) ? (1u << j) : 0u;
    }
    // byte g of per-pixel u64 word (bit j_global = g*8 + j), pixels P..P+3
    unsigned char* a = A1 + (size_t)P * 8 + g;
    a[0]  = (unsigned char)bp0;
    a[8]  = (unsigned char)bp1;
    a[16] = (unsigned char)bp2;
    a[24] = (unsigned char)bp3;
}

// ---- conv3x3, lane = pixel: 64ch bits -> 256ch bits (planar out) ----------
// grid 784, block 256 = 4 waves; wave = co-quarter, LANE = PIXEL.
// Taps + boundary masks in VGPRs (9 ds_reads/lane, once); weights wave-
// uniform via s_load (readfirstlane'd quarter). Per co:
//   y = 64*nv - 2*sum_t popc((a_t ^ w_t) & m_t)   (zero-padded tile).
// MERGE ORs Hin plane. DO_K3: A2 = sign(bn12(conv1x1(H, sgn w12))) via LDS
// exchange of the 4 quarters (exact-integer popcount, fp32 BN).
template <bool MERGE, bool DO_K3>
__global__ __launch_bounds__(256) void k_conv3c(
    const uint64_t* __restrict__ A, const uint64_t* __restrict__ Wb,
    const float2* __restrict__ ivbt, const uint64_t* __restrict__ Hin,
    uint64_t* __restrict__ Out,
    const uint64_t* __restrict__ W12b, const float2* __restrict__ iv12,
    unsigned short* __restrict__ A2)
{
    __shared__ uint64_t tile[4 * 58];
    __shared__ uint64_t sh4[4][64];
    const int l = threadIdx.x & 63;
    const int wv = threadIdx.x >> 6;
    const int wvu = __builtin_amdgcn_readfirstlane(wv);   // uniform quarter id
    const int chunk = blockIdx.x;            // 0..783
    const int b = chunk / 49;
    const int hw0 = (chunk % 49) * 64;
    const int r0 = hw0 / 56;
    const int o  = hw0 % 56;                 // 0..48 (chunk spans rows r0,r0+1)
    const int rfirst = r0 - 1;

    // stage zero-padded tile rows rfirst..rfirst+3, cols -1..56
    {
        int idx = threadIdx.x;
        if (idx < 4 * 58) {
            int rr = idx / 58, cc = idx % 58;
            int gh = rfirst + rr, gw = cc - 1;
            uint64_t v = 0;
            if ((unsigned)gh < 56u && (unsigned)gw < 56u)
                v = A[b * HW_ + gh * 56 + gw];
            tile[idx] = v;
        }
    }
    __syncthreads();

    // per-lane pixel coordinates
    const int inrow2 = (l >= 56 - o) ? 1 : 0;
    const int w = o + l - (inrow2 ? 56 : 0);
    const int row = r0 + inrow2;
    const int rbase = inrow2 * 58;

    // 9 taps + masks into VGPRs (once)
    uint64_t a[9], m[9];
    int nv = 0;
#pragma unroll
    for (int dr = 0; dr < 3; ++dr)
#pragma unroll
        for (int dc = 0; dc < 3; ++dc) {
            int t = dr * 3 + dc;
            a[t] = tile[rbase + dr * 58 + w + dc];   // zero-padded
            bool ok = ((unsigned)(row + dr - 1) < 56u) &&
                      ((unsigned)(w + dc - 1) < 56u);
            m[t] = ok ? ~0ull : 0ull;
            nv += ok;
        }
    const int base = 64 * nv;

    const uint64_t* wbase = Wb + wvu * 64 * 9;       // uniform
    const float2*   ivb   = ivbt + wvu * 64;         // uniform

    uint64_t bits = 0;
#pragma unroll 4
    for (int jo = 0; jo < 64; ++jo) {
        const uint64_t* wq = wbase + jo * 9;         // uniform -> s_load
        int s = 0;
#pragma unroll
        for (int t = 0; t < 9; ++t)
            s += (int)__popcll((a[t] ^ wq[t]) & m[t]);
        int y = base - 2 * s;
        float2 ib = ivb[jo];
        float val = __fadd_rn(__fmul_rn((float)y, ib.x), ib.y);
        bits |= (uint64_t)(val >= 0.0f) << jo;
    }

    size_t oidx = (size_t)wv * NPIX + (size_t)(b * HW_) + hw0 + l;
    if (MERGE) bits |= Hin[oidx];
    Out[oidx] = bits;

    if (DO_K3) {
        sh4[wv][l] = bits;
        __syncthreads();
        uint64_t h0 = sh4[0][l], h1 = sh4[1][l], h2 = sh4[2][l], h3 = sh4[3][l];
        unsigned bits16 = 0;
#pragma unroll
        for (int jj = 0; jj < 16; ++jj) {
            int cq = wvu * 16 + jj;                  // output channel 0..63
            const uint64_t* wq = W12b + cq * 4;      // uniform -> s_load
            int s = (int)(__popcll(h0 ^ wq[0]) + __popcll(h1 ^ wq[1]) +
                          __popcll(h2 ^ wq[2]) + __popcll(h3 ^ wq[3]));
            int y = 256 - 2 * s;
            float2 ibq = iv12[cq];
            float val = __fadd_rn(__fmul_rn((float)y, ibq.x), ibq.y);
            bits16 |= (val >= 0.0f) ? (1u << jj) : 0u;
        }
        // u16 quarter wv of A2[px] (bit cq = wv*16 + jj)
        A2[(size_t)(b * HW_ + hw0 + l) * 4 + wv] = (unsigned short)bits16;
    }
}

// ------------- K4b: OR-pool 2x2 (planar S) + write +-1.0f ------------------
__global__ __launch_bounds__(256) void k4b_pool(
    const uint64_t* __restrict__ S, float* __restrict__ out)
{
    int o = blockIdx.x * 256 + threadIdx.x;   // < 16*256*28*28 = 3211264
    int ow = o % 28;
    int t = o / 28;
    int oh = t % 28; t /= 28;
    int co = t & 255;
    int b  = t >> 8;
    int k = co >> 6, j = co & 63;
    const uint64_t* Sk = S + (size_t)k * NPIX + (size_t)(b * HW_) + (2 * oh) * 56 + 2 * ow;
    uint64_t s = Sk[0] | Sk[1] | Sk[56] | Sk[57];
    out[o] = ((s >> j) & 1) ? 1.0f : -1.0f;
}

// ---------------------------------------------------------------------------
extern "C" void kernel_launch(void* const* d_in, const int* in_sizes, int n_in,
                              void* d_out, int out_size, void* d_ws, size_t ws_size,
                              hipStream_t stream)
{
    const float* x   = (const float*)d_in[0];
    const float* w11 = (const float*)d_in[1];
    const float* w31 = (const float*)d_in[2];
    const float* w12 = (const float*)d_in[3];
    const float* w32 = (const float*)d_in[4];
    const float* g11 = (const float*)d_in[5];
    const float* b11 = (const float*)d_in[6];
    const float* m11 = (const float*)d_in[7];
    const float* v11 = (const float*)d_in[8];
    const float* g31 = (const float*)d_in[9];
    const float* b31 = (const float*)d_in[10];
    const float* m31 = (const float*)d_in[11];
    const float* v31 = (const float*)d_in[12];
    const float* g12 = (const float*)d_in[13];
    const float* b12 = (const float*)d_in[14];
    const float* m12 = (const float*)d_in[15];
    const float* v12 = (const float*)d_in[16];
    const float* g32 = (const float*)d_in[17];
    const float* b32 = (const float*)d_in[18];
    const float* m32 = (const float*)d_in[19];
    const float* v32 = (const float*)d_in[20];

    char* ws = (char*)d_ws;
    uint64_t* W31b = (uint64_t*)(ws + OFF_W31B);
    uint64_t* W12b = (uint64_t*)(ws + OFF_W12B);
    uint64_t* W32b = (uint64_t*)(ws + OFF_W32B);
    float2* iv11 = (float2*)(ws + OFF_IV11);
    float2* iv31 = (float2*)(ws + OFF_IV31);
    float2* iv12 = (float2*)(ws + OFF_IV12);
    float2* iv32 = (float2*)(ws + OFF_IV32);
    float*  sgnT = (float*)(ws + OFF_SGNT);
    uint64_t* A1 = (uint64_t*)(ws + OFF_A1);
    uint64_t* A2 = (uint64_t*)(ws + OFF_A2);
    uint64_t* Hb = (uint64_t*)(ws + OFF_H);
    uint64_t* Sb = (uint64_t*)(ws + OFF_S);

    k0_all<<<dim3(1283), dim3(256), 0, stream>>>(
        w11, w31, w12, w32,
        g11, b11, m11, v11, g31, b31, m31, v31,
        g12, b12, m12, v12, g32, b32, m32, v32,
        W31b, W12b, W32b, iv11, iv31, iv12, iv32, sgnT);

    k1_conv1<<<dim3(392), dim3(256), 0, stream>>>(x, sgnT, iv11, (unsigned char*)A1);

    // conv3 stage-2 with fused stage-3 conv1x1 (A2)
    k_conv3c<false, true><<<dim3(784), dim3(256), 0, stream>>>(
        A1, W31b, iv31, (const uint64_t*)nullptr, Hb,
        W12b, iv12, (unsigned short*)A2);

    // conv3 stage-4 with residual merge
    k_conv3c<true, false><<<dim3(784), dim3(256), 0, stream>>>(
        A2, W32b, iv32, Hb, Sb,
        (const uint64_t*)nullptr, (const float2*)nullptr, (unsigned short*)nullptr);

    k4b_pool<<<dim3(12544), dim3(256), 0, stream>>>(Sb, (float*)d_out);
}